// Round 4
// baseline (18.214 us; speedup 1.0000x reference)
//
#include <hip/hip_runtime.h>
#include <hip/hip_bf16.h>
#include <string.h>

// TaylorLayer via MFMA: out[B,8] = relu(W[8,164] @ epd[164,B] + b), B=262144.
// epd = monomials deg 1..3 of x[8], reference recursion order, T=164.
//
// R4: single kernel (prep_w folded in: A-fragments built per-lane from W
// with aligned float4 loads; row clamped to lane&7 so C rows 8..31 are
// garbage-but-unstored, avoiding masked loads). One wave-group of 32
// elements per wave, grid covers all 8192 groups (no grid-stride loop).
// Theory: R3's 17.6us (vs ~3us VALU model) = occupancy loss from VGPR
// pressure + 2-kernel graph overhead.
//
// MFMA: mfma_f32_32x32x16_bf16, A = Wperm (row=lane&31 -> out row, k-half
// h=lane>>5, slots 8i+j), B = monomial slots (col=lane&31, same k-map).
// K = 176, 12 zero-pad slots. C/D: col=lane&31, row=(reg&3)+8*(reg>>2)
// +4*(lane>>5) -> regs 0..3 = out rows 4h+0..3.

static constexpr int TEXP = 164;
static constexpr int NOUT = 8;
static constexpr int NMFMA = 11;   // K = 176
static constexpr int HALF = 88;    // monomial slots per k-half

using f32x16 = __attribute__((ext_vector_type(16))) float;
using short8 = __attribute__((ext_vector_type(8))) short;

// ---- compile-time monomial index math (reference t-order) ----
constexpr int rowstart2(int j) { return j * 8 - j * (j - 1) / 2; }
constexpr int start3(int j) {
  int s = 44;
  for (int jp = 0; jp < j; ++jp) s += (8 - jp) * (9 - jp) / 2;
  return s;
}
struct D3 { int j, p; };
constexpr D3 d3idx(int M) {
  int j = 0;
  while (start3(j + 1) <= M) ++j;
  int q = M - start3(j);
  int a = j;
  while (q >= (8 - a)) { q -= (8 - a); ++a; }
  int b = a + q;
  return { j, rowstart2(a) + (b - a) };
}

template <int M>
__device__ __forceinline__ float mono(const float (&xv)[8], const float (&d2)[36]) {
  if constexpr (M < 8) {
    return xv[M];
  } else if constexpr (M < 44) {
    return d2[M - 8];
  } else {
    constexpr D3 t = d3idx(M);
    return xv[t.j] * d2[t.p];
  }
}

__device__ __forceinline__ short bf16bits(float v) {
  __hip_bfloat16 h = __float2bfloat16(v);
  short s;
  memcpy(&s, &h, 2);
  return s;
}

template <int C>
__device__ __forceinline__ void do_slot(const float (&xv)[8], const float (&d2)[36],
                                        bool hi, short8& bv) {
  float v0 = mono<C>(xv, d2);
  float v1;
  if constexpr (HALF + C < TEXP) v1 = mono<HALF + C>(xv, d2);
  else v1 = 0.0f;
  float v = hi ? v1 : v0;
  bv[C & 7] = bf16bits(v);
}

template <int I>
__device__ __forceinline__ void slot8(const float (&xv)[8], const float (&d2)[36],
                                      bool hi, short8& bv) {
  do_slot<8 * I + 0>(xv, d2, hi, bv);
  do_slot<8 * I + 1>(xv, d2, hi, bv);
  do_slot<8 * I + 2>(xv, d2, hi, bv);
  do_slot<8 * I + 3>(xv, d2, hi, bv);
  do_slot<8 * I + 4>(xv, d2, hi, bv);
  do_slot<8 * I + 5>(xv, d2, hi, bv);
  do_slot<8 * I + 6>(xv, d2, hi, bv);
  do_slot<8 * I + 7>(xv, d2, hi, bv);
}

template <int I>
struct MfmaStep {
  static __device__ __forceinline__ void run(const float (&xv)[8], const float (&d2)[36],
                                             bool hi, const short8 (&af)[NMFMA],
                                             f32x16& acc) {
    short8 bv;
    slot8<I>(xv, d2, hi, bv);
    acc = __builtin_amdgcn_mfma_f32_32x32x16_bf16(af[I], bv, acc, 0, 0, 0);
    MfmaStep<I + 1>::run(xv, d2, hi, af, acc);
  }
};
template <>
struct MfmaStep<NMFMA> {
  static __device__ __forceinline__ void run(const float (&)[8], const float (&)[36],
                                             bool, const short8 (&)[NMFMA], f32x16&) {}
};

__global__ __launch_bounds__(256) void taylor_mfma(
    const float* __restrict__ x, const float* __restrict__ W,
    const float* __restrict__ b, float* __restrict__ out, int ngroups) {
  const int lane = (int)(threadIdx.x & 63);
  const bool hi = lane >= 32;
  const int h = hi ? 1 : 0;
  const int col = lane & 31;

  // ---- build A fragments from W (once per wave) ----
  // afrag[i][j] = bf16(W[row][88h + 8i + j]) for m<164 else 0; row=lane&7
  // (rows 8..31 of C are garbage, never stored).
  const int row = lane & 7;
  const float* wr = W + row * TEXP;
  const int mbase = h * HALF;

  short8 afrag[NMFMA];
#pragma unroll
  for (int i = 0; i < 9; ++i) {  // m = mbase+8i .. +7, all < 164
    float4 fa = *reinterpret_cast<const float4*>(wr + mbase + 8 * i);
    float4 fb = *reinterpret_cast<const float4*>(wr + mbase + 8 * i + 4);
    short8 f;
    f[0] = bf16bits(fa.x); f[1] = bf16bits(fa.y);
    f[2] = bf16bits(fa.z); f[3] = bf16bits(fa.w);
    f[4] = bf16bits(fb.x); f[5] = bf16bits(fb.y);
    f[6] = bf16bits(fb.z); f[7] = bf16bits(fb.w);
    afrag[i] = f;
  }
  {  // i = 9: h=0 -> m 72..79 all valid; h=1 -> m 160..163 valid, 164..167 -> 0
    float4 fa = *reinterpret_cast<const float4*>(wr + mbase + 72);
    float4 fb = *reinterpret_cast<const float4*>(wr + (hi ? 156 : 76));  // h=1 junk, zeroed below
    short8 f;
    f[0] = bf16bits(fa.x); f[1] = bf16bits(fa.y);
    f[2] = bf16bits(fa.z); f[3] = bf16bits(fa.w);
    f[4] = bf16bits(hi ? 0.0f : fb.x); f[5] = bf16bits(hi ? 0.0f : fb.y);
    f[6] = bf16bits(hi ? 0.0f : fb.z); f[7] = bf16bits(hi ? 0.0f : fb.w);
    afrag[9] = f;
  }
  {  // i = 10: h=0 -> m 80..87 valid; h=1 -> all 0 (load h=0 addr, select 0)
    float4 fa = *reinterpret_cast<const float4*>(wr + 80);
    float4 fb = *reinterpret_cast<const float4*>(wr + 84);
    short8 f;
    f[0] = bf16bits(hi ? 0.0f : fa.x); f[1] = bf16bits(hi ? 0.0f : fa.y);
    f[2] = bf16bits(hi ? 0.0f : fa.z); f[3] = bf16bits(hi ? 0.0f : fa.w);
    f[4] = bf16bits(hi ? 0.0f : fb.x); f[5] = bf16bits(hi ? 0.0f : fb.y);
    f[6] = bf16bits(hi ? 0.0f : fb.z); f[7] = bf16bits(hi ? 0.0f : fb.w);
    afrag[10] = f;
  }

  const float4 bv4 = *reinterpret_cast<const float4*>(b + 4 * h);

  const int g = (int)((blockIdx.x * blockDim.x + threadIdx.x) >> 6);
  if (g >= ngroups) return;

  const int elem = g * 32 + col;
  float4 xa = reinterpret_cast<const float4*>(x)[elem * 2 + 0];
  float4 xb = reinterpret_cast<const float4*>(x)[elem * 2 + 1];
  float xv[8] = {xa.x, xa.y, xa.z, xa.w, xb.x, xb.y, xb.z, xb.w};

  float d2[36];
#pragma unroll
  for (int j = 0; j < 8; ++j) {
#pragma unroll
    for (int k = j; k < 8; ++k) {
      d2[rowstart2(j) + (k - j)] = xv[j] * xv[k];
    }
  }

  f32x16 acc;
#pragma unroll
  for (int r = 0; r < 16; ++r) acc[r] = 0.0f;

  MfmaStep<0>::run(xv, d2, hi, afrag, acc);

  float4 o;
  o.x = fmaxf(acc[0] + bv4.x, 0.0f);
  o.y = fmaxf(acc[1] + bv4.y, 0.0f);
  o.z = fmaxf(acc[2] + bv4.z, 0.0f);
  o.w = fmaxf(acc[3] + bv4.w, 0.0f);
  *reinterpret_cast<float4*>(out + elem * 8 + 4 * h) = o;
}

extern "C" void kernel_launch(void* const* d_in, const int* in_sizes, int n_in,
                              void* d_out, int out_size, void* d_ws, size_t ws_size,
                              hipStream_t stream) {
  const float* x = (const float*)d_in[0];   // [262144, 8, 1]
  const float* W = (const float*)d_in[1];   // [8, 164]
  const float* b = (const float*)d_in[2];   // [8, 1]
  float* out = (float*)d_out;               // [262144, 8]

  int n = in_sizes[0] / 8;      // 262144 elements
  int ngroups = n / 32;         // 8192 wave-groups
  int waves_per_block = 4;      // 256 threads
  int blocks = (ngroups + waves_per_block - 1) / waves_per_block;  // 2048
  taylor_mfma<<<blocks, 256, 0, stream>>>(x, W, b, out, ngroups);
}

// Round 5
// 17.257 us; speedup vs baseline: 1.0554x; 1.0554x over previous
//
#include <hip/hip_runtime.h>
#include <hip/hip_bf16.h>
#include <string.h>

// TaylorLayer via MFMA: out[B,8] = relu(W[8,164] @ epd[164,B] + b), B=262144.
// epd = monomials deg 1..3 of x[8], reference recursion order, T=164.
//
// R5: attack register pressure (the untested hypothesis for R3/R4's 18us
// vs ~4us model):
//  - prep_w kernel (R3-validated) writes bf16 Wperm to d_ws; main kernel
//    loads ONE short8 (16B) per MFMA step, double-buffered (8 VGPR total)
//    instead of 44 persistent VGPR + 88 cvts.
//  - sched_barrier(0) between steps pins each step's slot-compute next to
//    its MFMA -> no cross-step hoisting -> short live ranges.
//  - __launch_bounds__(256,4): VGPR <= 128 -> 4 waves/SIMD.
// Persistent live set ~76 VGPR (xv 8, d2 36, acc 16, af 2x4, bias 4).
//
// MFMA mfma_f32_32x32x16_bf16, K=176 (12 zero-pad slots).
// A: row=lane&31 (rows 8..31 zeroed in prep), k-half h=lane>>5, slot 8i+j.
// B: col=lane&31, same k-map (A/B symmetric).
// C/D: col=lane&31, row=(reg&3)+8*(reg>>2)+4*(lane>>5) -> regs 0..3 = rows
// 4h+0..3 -> one float4 store per lane.

static constexpr int TEXP = 164;
static constexpr int NOUT = 8;
static constexpr int NMFMA = 11;   // K = 176
static constexpr int HALF = 88;    // monomial slots per k-half

using f32x16 = __attribute__((ext_vector_type(16))) float;
using short8 = __attribute__((ext_vector_type(8))) short;

// ---- compile-time monomial index math (reference t-order) ----
constexpr int rowstart2(int j) { return j * 8 - j * (j - 1) / 2; }
constexpr int start3(int j) {
  int s = 44;
  for (int jp = 0; jp < j; ++jp) s += (8 - jp) * (9 - jp) / 2;
  return s;
}
struct D3 { int j, p; };
constexpr D3 d3idx(int M) {
  int j = 0;
  while (start3(j + 1) <= M) ++j;
  int q = M - start3(j);
  int a = j;
  while (q >= (8 - a)) { q -= (8 - a); ++a; }
  int b = a + q;
  return { j, rowstart2(a) + (b - a) };
}

template <int M>
__device__ __forceinline__ float mono(const float (&xv)[8], const float (&d2)[36]) {
  if constexpr (M < 8) {
    return xv[M];
  } else if constexpr (M < 44) {
    return d2[M - 8];
  } else {
    constexpr D3 t = d3idx(M);
    return xv[t.j] * d2[t.p];
  }
}

__device__ __forceinline__ short bf16bits(float v) {
  __hip_bfloat16 h = __float2bfloat16(v);
  short s;
  memcpy(&s, &h, 2);
  return s;
}

template <int C>
__device__ __forceinline__ void do_slot(const float (&xv)[8], const float (&d2)[36],
                                        bool hi, short8& bv) {
  float v0 = mono<C>(xv, d2);
  float v1;
  if constexpr (HALF + C < TEXP) v1 = mono<HALF + C>(xv, d2);
  else v1 = 0.0f;
  float v = hi ? v1 : v0;
  bv[C & 7] = bf16bits(v);
}

template <int I>
__device__ __forceinline__ void slot8(const float (&xv)[8], const float (&d2)[36],
                                      bool hi, short8& bv) {
  do_slot<8 * I + 0>(xv, d2, hi, bv);
  do_slot<8 * I + 1>(xv, d2, hi, bv);
  do_slot<8 * I + 2>(xv, d2, hi, bv);
  do_slot<8 * I + 3>(xv, d2, hi, bv);
  do_slot<8 * I + 4>(xv, d2, hi, bv);
  do_slot<8 * I + 5>(xv, d2, hi, bv);
  do_slot<8 * I + 6>(xv, d2, hi, bv);
  do_slot<8 * I + 7>(xv, d2, hi, bv);
}

template <int I>
struct MfmaStep {
  static __device__ __forceinline__ void run(const float (&xv)[8], const float (&d2)[36],
                                             bool hi, const unsigned short* __restrict__ wpl,
                                             short8 af_cur, f32x16& acc) {
    short8 af_next;
    if constexpr (I + 1 < NMFMA)
      af_next = *reinterpret_cast<const short8*>(wpl + (I + 1) * 64 * 8);
    short8 bv;
    slot8<I>(xv, d2, hi, bv);
    acc = __builtin_amdgcn_mfma_f32_32x32x16_bf16(af_cur, bv, acc, 0, 0, 0);
    __builtin_amdgcn_sched_barrier(0);
    if constexpr (I + 1 < NMFMA)
      MfmaStep<I + 1>::run(xv, d2, hi, wpl, af_next, acc);
  }
};

// ---- prep: Wperm bf16 in A-frag slot order (R3-validated):
// wp[(i*64+lane)*8 + j] = bf16(W[row][88h + 8i + j]), row=lane&31 (0 if
// row>=8), h=lane>>5 (0 if slot >= 164) ----
__global__ void prep_w(const float* __restrict__ W, unsigned short* __restrict__ wp) {
  for (int idx = threadIdx.x + blockIdx.x * blockDim.x; idx < NMFMA * 64 * 8;
       idx += blockDim.x * gridDim.x) {
    int j = idx & 7;
    int lane = (idx >> 3) & 63;
    int i = idx >> 9;
    int row = lane & 31, h = lane >> 5;
    int m = HALF * h + 8 * i + j;
    float v = (row < NOUT && m < TEXP) ? W[row * TEXP + m] : 0.0f;
    union { float f; unsigned int u; } c; c.f = v;
    unsigned int u = c.u;
    wp[idx] = (unsigned short)((u + 0x7fffu + ((u >> 16) & 1u)) >> 16);  // RNE
  }
}

__global__ __launch_bounds__(256, 4) void taylor_mfma(
    const float* __restrict__ x, const float* __restrict__ b,
    const unsigned short* __restrict__ wp, float* __restrict__ out, int ngroups) {
  const int lane = (int)(threadIdx.x & 63);
  const bool hi = lane >= 32;
  const int h = hi ? 1 : 0;
  const int col = lane & 31;

  const unsigned short* wpl = wp + lane * 8;  // per-lane A-frag stream
  short8 af0 = *reinterpret_cast<const short8*>(wpl);  // step 0 fragment

  const float4 bv4 = *reinterpret_cast<const float4*>(b + 4 * h);

  const int g = (int)((blockIdx.x * blockDim.x + threadIdx.x) >> 6);
  if (g >= ngroups) return;

  const int elem = g * 32 + col;
  float4 xa = reinterpret_cast<const float4*>(x)[elem * 2 + 0];
  float4 xb = reinterpret_cast<const float4*>(x)[elem * 2 + 1];
  float xv[8] = {xa.x, xa.y, xa.z, xa.w, xb.x, xb.y, xb.z, xb.w};

  float d2[36];
#pragma unroll
  for (int j = 0; j < 8; ++j) {
#pragma unroll
    for (int k = j; k < 8; ++k) {
      d2[rowstart2(j) + (k - j)] = xv[j] * xv[k];
    }
  }

  f32x16 acc;
#pragma unroll
  for (int r = 0; r < 16; ++r) acc[r] = 0.0f;

  MfmaStep<0>::run(xv, d2, hi, wpl, af0, acc);

  float4 o;
  o.x = fmaxf(acc[0] + bv4.x, 0.0f);
  o.y = fmaxf(acc[1] + bv4.y, 0.0f);
  o.z = fmaxf(acc[2] + bv4.z, 0.0f);
  o.w = fmaxf(acc[3] + bv4.w, 0.0f);
  *reinterpret_cast<float4*>(out + elem * 8 + 4 * h) = o;
}

extern "C" void kernel_launch(void* const* d_in, const int* in_sizes, int n_in,
                              void* d_out, int out_size, void* d_ws, size_t ws_size,
                              hipStream_t stream) {
  const float* x = (const float*)d_in[0];   // [262144, 8, 1]
  const float* W = (const float*)d_in[1];   // [8, 164]
  const float* b = (const float*)d_in[2];   // [8, 1]
  float* out = (float*)d_out;               // [262144, 8]
  unsigned short* wp = (unsigned short*)d_ws;  // 11*64*8 bf16 = 11264 B

  int n = in_sizes[0] / 8;      // 262144 elements
  int ngroups = n / 32;         // 8192 wave-groups
  int blocks = ngroups / 4;     // 4 waves per block -> 2048 blocks

  prep_w<<<8, 256, 0, stream>>>(W, wp);
  taylor_mfma<<<blocks, 256, 0, stream>>>(x, b, wp, out, ngroups);
}